// Round 4
// baseline (533.949 us; speedup 1.0000x reference)
//
#include <hip/hip_runtime.h>
#include <hip/hip_bf16.h>
#include <math.h>

#define B_SZ    4
#define S_LEN   4096
#define DMODEL  1024
#define NH      16
#define KDIM    64
#define NF      256
#define NROWS   (B_SZ * S_LEN)          // 16384
#define RFF_SCALE 0.08838834764831845f  // sqrt(2/256)
#define NORM_Q    0.125f                // 1/sqrt(64)
#define VT_STRIDE ((size_t)(80 * 4096)) // per-bh vT elems

typedef __attribute__((ext_vector_type(8))) short s8v;
typedef __attribute__((ext_vector_type(4))) float f4v;

static __device__ __forceinline__ unsigned short f2bf(float f) {
  unsigned u = __float_as_uint(f);
  unsigned r = (u + 0x7FFFu + ((u >> 16) & 1u)) >> 16;   // RNE
  return (unsigned short)r;
}

#define MFMA16(a, b, c) __builtin_amdgcn_mfma_f32_16x16x32_bf16((a), (b), (c), 0, 0, 0)

__device__ __forceinline__ void glds16(const void* g, void* l) {
  __builtin_amdgcn_global_load_lds(
      (const __attribute__((address_space(1))) void*)g,
      (__attribute__((address_space(3))) void*)l, 16, 0, 0);
}

// ---------------------------------------------------------------------------
__global__ __launch_bounds__(256) void cast_bf16_kernel(
    const float* __restrict__ src, unsigned short* __restrict__ dst, int n8)
{
  int i = blockIdx.x * 256 + threadIdx.x;
  if (i >= n8) return;
  const float* s = src + (size_t)i * 8;
  float4 a = *(const float4*)s;
  float4 b = *(const float4*)(s + 4);
  union { s8v v; unsigned short u[8]; } o;
  o.u[0]=f2bf(a.x); o.u[1]=f2bf(a.y); o.u[2]=f2bf(a.z); o.u[3]=f2bf(a.w);
  o.u[4]=f2bf(b.x); o.u[5]=f2bf(b.y); o.u[6]=f2bf(b.z); o.u[7]=f2bf(b.w);
  *(s8v*)(dst + (size_t)i * 8) = o.v;
}

__global__ __launch_bounds__(256) void transpose_cast_kernel(
    const float* __restrict__ W, unsigned short* __restrict__ WT)
{
  __shared__ float t[32][33];
  const int k0 = blockIdx.y * 32, n0 = blockIdx.x * 32;
  const int c = threadIdx.x & 31, r4 = threadIdx.x >> 5;
#pragma unroll
  for (int i = 0; i < 4; ++i) {
    int row = r4 + i * 8;
    t[row][c] = W[(size_t)(k0 + row) * 1024 + n0 + c];
  }
  __syncthreads();
#pragma unroll
  for (int i = 0; i < 4; ++i) {
    int row = r4 + i * 8;
    WT[(size_t)(n0 + row) * 1024 + k0 + c] = f2bf(t[c][row]);
  }
}

__global__ __launch_bounds__(256) void prep_rff_kernel(
    const float* __restrict__ rffW, unsigned short* __restrict__ rffWT)
{
  int i = blockIdx.x * 256 + threadIdx.x;   // 16384
  int f = i >> 6, d = i & 63;
  rffWT[(size_t)f * 64 + d] = f2bf(rffW[(size_t)d * 256 + f] * NORM_Q);
}

// vT rows 64..79 per bh: row 64 = 1.0 (bf16), rows 65..79 = 0
__global__ __launch_bounds__(256) void init_vT_kernel(unsigned short* __restrict__ vT)
{
  int i = (blockIdx.x * 256 + threadIdx.x) * 8;   // 0 .. 64*16*4096
  int bh = i >> 16;           // 16*4096 shorts per bh
  int rem = i & 65535;
  int d = rem >> 12;          // 0..15 -> actual 64+d
  unsigned short val = (d == 0) ? (unsigned short)0x3F80 : (unsigned short)0;
  union { s8v v; unsigned short u[8]; } o;
#pragma unroll
  for (int j = 0; j < 8; ++j) o.u[j] = val;
  *(s8v*)(vT + (size_t)bh * VT_STRIDE + (size_t)(64 + d) * 4096 + (rem & 4095)) = o.v;
}

// ---------------------------------------------------------------------------
// bf16 MFMA GEMM: C = A @ BT^T + bias. 128x128 tile, BK=32, glds staging.
// QKV_FUSED: which==2 (v) is stored TRANSPOSED to vT[bh][d][s] via LDS.
// ---------------------------------------------------------------------------
template <int OUT_BF16, int QKV_FUSED>
__global__ __launch_bounds__(256) void gemm_bt_kernel(
    const unsigned short* __restrict__ A,
    const unsigned short* __restrict__ BT0,
    const unsigned short* __restrict__ BT1,
    const unsigned short* __restrict__ BT2,
    const float* __restrict__ bias0, const float* __restrict__ bias1,
    const float* __restrict__ bias2,
    void* __restrict__ out0, void* __restrict__ out1, void* __restrict__ out2,
    int M, int N, int K)
{
  __shared__ __align__(16) unsigned short lds[8192];   // As = lds, Bs = lds+4096
  const int tid = threadIdx.x;
  const int lane = tid & 63, wave = tid >> 6;
  const int m0 = blockIdx.y * 128;
  int ngl = blockIdx.x * 128;
  const unsigned short* BT = BT0;
  const float* bias = bias0;
  void* outp = out0;
  int which = 0;
  if (QKV_FUSED) {
    which = ngl >> 10;
    if (which == 1) { BT = BT1; bias = bias1; outp = out1; }
    else if (which == 2) { BT = BT2; bias = bias2; outp = out2; }
    ngl &= 1023;
  }
  const int n0 = ngl;
  const int wm = (wave >> 1) * 64, wn = (wave & 1) * 64;
  const int col = lane & 15, quad = lane >> 4;

  f4v acc[4][4];
  const f4v zz = {0.f, 0.f, 0.f, 0.f};
#pragma unroll
  for (int i = 0; i < 4; ++i)
#pragma unroll
    for (int j = 0; j < 4; ++j) acc[i][j] = zz;

  for (int k0 = 0; k0 < K; k0 += 32) {
#pragma unroll
    for (int i = 0; i < 2; ++i) {
      int cb = i * 256 + wave * 64;
      int c  = cb + lane;
      int row = c >> 2, ch = c & 3;
      glds16(A  + (size_t)(m0 + row) * K + k0 + ch * 8, &lds[cb * 8]);
      glds16(BT + (size_t)(n0 + row) * K + k0 + ch * 8, &lds[4096 + cb * 8]);
    }
    __syncthreads();
    s8v af[4], bf[4];
#pragma unroll
    for (int t = 0; t < 4; ++t) {
      af[t] = *(const s8v*)&lds[(wm + t * 16 + col) * 32 + quad * 8];
      bf[t] = *(const s8v*)&lds[4096 + (wn + t * 16 + col) * 32 + quad * 8];
    }
#pragma unroll
    for (int i = 0; i < 4; ++i)
#pragma unroll
      for (int j = 0; j < 4; ++j)
        acc[i][j] = MFMA16(af[i], bf[j], acc[i][j]);
    __syncthreads();
  }

  if (QKV_FUSED && which == 2) {
    // transposed store of v into vT[bh][d][s] via per-wave LDS scratch
    unsigned short* scr = &lds[wave * 2048];   // [64 n][32 m]
    unsigned short* vTg = (unsigned short*)outp;
    const int b2 = m0 >> 12;
    const int sb = (m0 & 4095) + wm;
#pragma unroll
    for (int ip = 0; ip < 2; ++ip) {
#pragma unroll
      for (int j = 0; j < 4; ++j) {
        float bv = bias[n0 + wn + j * 16 + col];
#pragma unroll
        for (int i2 = 0; i2 < 2; ++i2) {
          int i = ip * 2 + i2;
          ushort4 pk;
          pk.x = f2bf(acc[i][j][0] + bv);
          pk.y = f2bf(acc[i][j][1] + bv);
          pk.z = f2bf(acc[i][j][2] + bv);
          pk.w = f2bf(acc[i][j][3] + bv);
          *(ushort4*)&scr[(j * 16 + col) * 32 + i2 * 16 + quad * 4] = pk;
        }
      }
#pragma unroll
      for (int rr = 0; rr < 2; ++rr) {
        int nIn = (lane >> 1) + rr * 32;
        int half = lane & 1;
        int ng = n0 + wn + nIn;          // 0..1023 within v
        s8v c0 = *(const s8v*)&scr[nIn * 32 + half * 8];
        s8v c1 = *(const s8v*)&scr[nIn * 32 + half * 8 + 16];
        size_t vbase = (size_t)(b2 * 16 + (ng >> 6)) * VT_STRIDE
                     + (size_t)(ng & 63) * 4096 + sb + ip * 32;
        *(s8v*)(vTg + vbase + half * 8)      = c0;
        *(s8v*)(vTg + vbase + half * 8 + 16) = c1;
      }
    }
    return;
  }

#pragma unroll
  for (int i = 0; i < 4; ++i) {
#pragma unroll
    for (int j = 0; j < 4; ++j) {
      int n = n0 + wn + j * 16 + col;
      float bv = bias[n];
#pragma unroll
      for (int r = 0; r < 4; ++r) {
        int m = m0 + wm + i * 16 + quad * 4 + r;
        float v = acc[i][j][r] + bv;
        if (OUT_BF16)
          ((unsigned short*)outp)[(size_t)m * N + n] = f2bf(v);
        else
          ((float*)outp)[(size_t)m * N + n] = v;
      }
    }
  }
}

// ---------------------------------------------------------------------------
// kv kernel: grid (64 bh, 16 chunks of 256 rows).
//   pkv[chunk][bh][f][d<80] = sum_s k'[s,f]*vT[d,s]  (vT row 64 = ones)
// LDS = kps only (36 KB). k A-frags + vT B-frags from global; W in registers.
// ---------------------------------------------------------------------------
__global__ __launch_bounds__(256) void kv_kernel(
    const unsigned short* __restrict__ kg, const unsigned short* __restrict__ vTg,
    const unsigned short* __restrict__ rffWT, const float* __restrict__ rffb,
    float* __restrict__ pkv)
{
  __shared__ __align__(16) unsigned short kps[256 * 72];  // k'^T [f][s]
  const int bh = blockIdx.x, chunk = blockIdx.y;
  const int b = bh >> 4, h = bh & 15;
  const int tid = threadIdx.x;
  const int lane = tid & 63, wave = tid >> 6;
  const int col = lane & 15, quad = lane >> 4;
  const f4v zz = {0.f, 0.f, 0.f, 0.f};

  s8v wf[2][4];
  float bfv[4];
#pragma unroll
  for (int ks = 0; ks < 2; ++ks)
#pragma unroll
    for (int t = 0; t < 4; ++t)
      wf[ks][t] = *(const s8v*)(rffWT +
          (size_t)(wave * 64 + t * 16 + col) * 64 + ks * 32 + quad * 8);
#pragma unroll
  for (int j = 0; j < 4; ++j) bfv[j] = rffb[wave * 64 + j * 16 + col];

  const unsigned short* vbh = vTg + (size_t)bh * VT_STRIDE;

  f4v kvacc[4][5];
#pragma unroll
  for (int i = 0; i < 4; ++i)
#pragma unroll
    for (int j = 0; j < 5; ++j) kvacc[i][j] = zz;

  for (int st = 0; st < 4; ++st) {
    const int s0 = chunk * 256 + st * 64;
    // proj: A = k rows (global), B = W (regs) -> D[s][f]
    f4v p[4][4];
#pragma unroll
    for (int i = 0; i < 4; ++i)
#pragma unroll
      for (int j = 0; j < 4; ++j) p[i][j] = zz;
#pragma unroll
    for (int ks = 0; ks < 2; ++ks) {
      s8v af[4];
#pragma unroll
      for (int t = 0; t < 4; ++t)
        af[t] = *(const s8v*)(kg +
            ((size_t)(b * S_LEN + s0 + t * 16 + col)) * DMODEL + h * KDIM + ks * 32 + quad * 8);
#pragma unroll
      for (int i = 0; i < 4; ++i)
#pragma unroll
        for (int j = 0; j < 4; ++j) p[i][j] = MFMA16(af[i], wf[ks][j], p[i][j]);
    }
    __syncthreads();   // prev kv-MFMA done reading kps
    // cos epilogue -> kps[f][s], packed 8B (s = i*16+quad*4+r, r contiguous)
#pragma unroll
    for (int j = 0; j < 4; ++j) {
      int f = wave * 64 + j * 16 + col;
#pragma unroll
      for (int i = 0; i < 4; ++i) {
        ushort4 pk;
        pk.x = f2bf(__cosf(p[i][j][0] + bfv[j]) * RFF_SCALE);
        pk.y = f2bf(__cosf(p[i][j][1] + bfv[j]) * RFF_SCALE);
        pk.z = f2bf(__cosf(p[i][j][2] + bfv[j]) * RFF_SCALE);
        pk.w = f2bf(__cosf(p[i][j][3] + bfv[j]) * RFF_SCALE);
        *(ushort4*)&kps[f * 72 + i * 16 + quad * 4] = pk;
      }
    }
    // vT B-frags from global (independent of LDS -> overlap barrier wait)
    s8v bf[2][5];
#pragma unroll
    for (int ks = 0; ks < 2; ++ks)
#pragma unroll
      for (int t = 0; t < 5; ++t)
        bf[ks][t] = *(const s8v*)(vbh +
            (size_t)(t * 16 + col) * 4096 + s0 + ks * 32 + quad * 8);
    __syncthreads();   // kps visible
#pragma unroll
    for (int ks = 0; ks < 2; ++ks) {
      s8v af[4];
#pragma unroll
      for (int t = 0; t < 4; ++t)
        af[t] = *(const s8v*)&kps[(wave * 64 + t * 16 + col) * 72 + ks * 32 + quad * 8];
#pragma unroll
      for (int i = 0; i < 4; ++i)
#pragma unroll
        for (int j = 0; j < 5; ++j)
          kvacc[i][j] = MFMA16(af[i], bf[ks][j], kvacc[i][j]);
    }
  }
  const size_t base = ((size_t)(chunk * 64 + bh)) * NF * 80;
#pragma unroll
  for (int i = 0; i < 4; ++i)
#pragma unroll
    for (int r = 0; r < 4; ++r) {
      int f = wave * 64 + i * 16 + quad * 4 + r;
#pragma unroll
      for (int j = 0; j < 5; ++j)
        pkv[base + (size_t)f * 80 + j * 16 + col] = kvacc[i][j][r];
    }
}

// ---------------------------------------------------------------------------
// reduce 16 chunk partials, transpose -> kvT bf16 [bh][80 d][256 f]
// ---------------------------------------------------------------------------
__global__ __launch_bounds__(256) void reduce_kv_kernel(
    const float* __restrict__ pkv, unsigned short* __restrict__ kvT)
{
  __shared__ unsigned short lt[80 * 256];
  const int bh = blockIdx.x;
  for (int e = threadIdx.x; e < NF * 80; e += 256) {
    float s = 0.f;
#pragma unroll
    for (int c = 0; c < 16; ++c)
      s += pkv[((size_t)(c * 64 + bh)) * NF * 80 + e];
    int f = e / 80, d = e - f * 80;
    lt[d * 256 + f] = f2bf(s);
  }
  __syncthreads();
  for (int o = threadIdx.x; o < 80 * NF; o += 256)
    kvT[(size_t)bh * 80 * NF + o] = lt[o];
}

// ---------------------------------------------------------------------------
// attn kernel: grid (64 bh, 16), 4 x 64-row tiles per block.
// proj computed TRANSPOSED (A=W, B=q -> D[f][s]) so qps writes pack as 8B.
// ---------------------------------------------------------------------------
__global__ __launch_bounds__(256) void attn_kernel(
    const unsigned short* __restrict__ qg, const unsigned short* __restrict__ kvTg,
    const unsigned short* __restrict__ rffWT, const float* __restrict__ rffb,
    unsigned short* __restrict__ att)
{
  __shared__ __align__(16) unsigned short qps[64 * 264];   // q' [s][f]
  __shared__ __align__(16) unsigned short kvs[80 * 264];   // kvT [d][f]
  const int bh = blockIdx.x;
  const int b = bh >> 4, h = bh & 15;
  const int tid = threadIdx.x;
  const int lane = tid & 63, wave = tid >> 6;
  const int col = lane & 15, quad = lane >> 4;
  const f4v zz = {0.f, 0.f, 0.f, 0.f};

  s8v wf[2][4];
  float barr[4][4];
#pragma unroll
  for (int ks = 0; ks < 2; ++ks)
#pragma unroll
    for (int t = 0; t < 4; ++t)
      wf[ks][t] = *(const s8v*)(rffWT +
          (size_t)(wave * 64 + t * 16 + col) * 64 + ks * 32 + quad * 8);
#pragma unroll
  for (int i = 0; i < 4; ++i) {
    float4 b4 = *(const float4*)&rffb[wave * 64 + i * 16 + quad * 4];
    barr[i][0] = b4.x; barr[i][1] = b4.y; barr[i][2] = b4.z; barr[i][3] = b4.w;
  }

  for (int c = tid; c < 2560; c += 256) {
    int d = c >> 5, ch = c & 31;
    *(s8v*)&kvs[d * 264 + ch * 8] =
        *(const s8v*)(kvTg + (size_t)bh * 80 * NF + d * 256 + ch * 8);
  }

  for (int it = 0; it < 4; ++it) {
    const int s0 = (blockIdx.y * 4 + it) * 64;
    // proj^T: A = W (regs, m=f), B = q rows (global, n=s) -> D[f][s]
    f4v p[4][4];
#pragma unroll
    for (int i = 0; i < 4; ++i)
#pragma unroll
      for (int j = 0; j < 4; ++j) p[i][j] = zz;
#pragma unroll
    for (int ks = 0; ks < 2; ++ks) {
      s8v qf[4];
#pragma unroll
      for (int t = 0; t < 4; ++t)
        qf[t] = *(const s8v*)(qg +
            ((size_t)(b * S_LEN + s0 + t * 16 + col)) * DMODEL + h * KDIM + ks * 32 + quad * 8);
#pragma unroll
      for (int i = 0; i < 4; ++i)
#pragma unroll
        for (int j = 0; j < 4; ++j) p[i][j] = MFMA16(wf[ks][i], qf[j], p[i][j]);
    }
    __syncthreads();   // prev num-MFMA done reading qps; fences kvs stage on it==0
    // cos epilogue -> qps[s][f], packed 8B (f = i*16+quad*4+r contiguous)
#pragma unroll
    for (int j = 0; j < 4; ++j) {
      int s = j * 16 + col;
#pragma unroll
      for (int i = 0; i < 4; ++i) {
        ushort4 pk;
        pk.x = f2bf(__cosf(p[i][j][0] + barr[i][0]) * RFF_SCALE);
        pk.y = f2bf(__cosf(p[i][j][1] + barr[i][1]) * RFF_SCALE);
        pk.z = f2bf(__cosf(p[i][j][2] + barr[i][2]) * RFF_SCALE);
        pk.w = f2bf(__cosf(p[i][j][3] + barr[i][3]) * RFF_SCALE);
        *(ushort4*)&qps[s * 264 + wave * 64 + i * 16 + quad * 4] = pk;
      }
    }
    __syncthreads();
    // num: A = qps rows wave*16..+15, B = kvs, K=256
    f4v acc[5];
#pragma unroll
    for (int j = 0; j < 5; ++j) acc[j] = zz;
#pragma unroll
    for (int k0 = 0; k0 < 256; k0 += 32) {
      s8v af = *(const s8v*)&qps[(wave * 16 + col) * 264 + k0 + quad * 8];
      s8v bf[5];
#pragma unroll
      for (int t = 0; t < 5; ++t)
        bf[t] = *(const s8v*)&kvs[(t * 16 + col) * 264 + k0 + quad * 8];
#pragma unroll
      for (int j = 0; j < 5; ++j) acc[j] = MFMA16(af, bf[j], acc[j]);
    }
    float inv[4];
#pragma unroll
    for (int r = 0; r < 4; ++r) {
      float den = __shfl(acc[4][r], lane & 48);
      inv[r] = 1.0f / (den + 1e-6f);
    }
#pragma unroll
    for (int r = 0; r < 4; ++r) {
      int m = s0 + wave * 16 + quad * 4 + r;
      size_t obase = ((size_t)(b * S_LEN + m)) * DMODEL + h * KDIM;
#pragma unroll
      for (int j = 0; j < 4; ++j)
        att[obase + j * 16 + col] = f2bf(acc[j][r] * inv[r]);
    }
  }
}

// ---------------------------------------------------------------------------
extern "C" void kernel_launch(void* const* d_in, const int* in_sizes, int n_in,
                              void* d_out, int out_size, void* d_ws, size_t ws_size,
                              hipStream_t stream)
{
  const float* x    = (const float*)d_in[0];
  const float* Wq   = (const float*)d_in[1];
  const float* bq   = (const float*)d_in[2];
  const float* Wk   = (const float*)d_in[3];
  const float* bk   = (const float*)d_in[4];
  const float* Wv   = (const float*)d_in[5];
  const float* bv   = (const float*)d_in[6];
  const float* rffW = (const float*)d_in[7];
  const float* rffb = (const float*)d_in[8];
  const float* Wo   = (const float*)d_in[9];
  const float* bo   = (const float*)d_in[10];
  float* out = (float*)d_out;

  char* w = (char*)d_ws;
  const size_t XB  = (size_t)NROWS * DMODEL * 2;    // 33,554,432
  const size_t WT  = (size_t)DMODEL * DMODEL * 2;   // 2,097,152
  const size_t VTB = (size_t)64 * VT_STRIDE * 2;    // 41,943,040
  unsigned short* xb   = (unsigned short*)(w);
  unsigned short* WqT  = (unsigned short*)(w + XB);
  unsigned short* WkT  = (unsigned short*)(w + XB + WT);
  unsigned short* WvT  = (unsigned short*)(w + XB + 2 * WT);
  unsigned short* WoT  = (unsigned short*)(w + XB + 3 * WT);
  unsigned short* rWT  = (unsigned short*)(w + XB + 4 * WT);
  char* p = w + XB + 4 * WT + 65536;
  unsigned short* qb  = (unsigned short*)(p);
  unsigned short* kb  = (unsigned short*)(p + XB);
  unsigned short* vTg = (unsigned short*)(p + 2 * XB);
  float* pkv          = (float*)(p + 2 * XB + VTB);
  unsigned short* kvT = (unsigned short*)(p + 2 * XB + VTB + (size_t)16 * 64 * NF * 80 * 4);
  unsigned short* att = kb;   // kb consumed before attn writes

  cast_bf16_kernel<<<NROWS * DMODEL / 8 / 256, 256, 0, stream>>>(x, xb, NROWS * DMODEL / 8);
  dim3 tg(32, 32);
  transpose_cast_kernel<<<tg, 256, 0, stream>>>(Wq, WqT);
  transpose_cast_kernel<<<tg, 256, 0, stream>>>(Wk, WkT);
  transpose_cast_kernel<<<tg, 256, 0, stream>>>(Wv, WvT);
  transpose_cast_kernel<<<tg, 256, 0, stream>>>(Wo, WoT);
  prep_rff_kernel<<<64, 256, 0, stream>>>(rffW, rWT);
  init_vT_kernel<<<2048, 256, 0, stream>>>(vTg);

  gemm_bt_kernel<1, 1><<<dim3(24, 128), 256, 0, stream>>>(
      xb, WqT, WkT, WvT, bq, bk, bv, qb, kb, vTg, NROWS, DMODEL, DMODEL);

  kv_kernel<<<dim3(64, 16), 256, 0, stream>>>(kb, vTg, rWT, rffb, pkv);
  reduce_kv_kernel<<<64, 256, 0, stream>>>(pkv, kvT);
  attn_kernel<<<dim3(64, 16), 256, 0, stream>>>(qb, kvT, rWT, rffb, att);

  gemm_bt_kernel<0, 0><<<dim3(8, 128), 256, 0, stream>>>(
      att, WoT, nullptr, nullptr, bo, nullptr, nullptr, out, nullptr, nullptr,
      NROWS, DMODEL, DMODEL);
}